// Round 11
// baseline (571.099 us; speedup 1.0000x reference)
//
#include <hip/hip_runtime.h>

#define USER_NUM 100000
#define ITEM_NUM 150000
#define NTOT     250000           // USER_NUM + ITEM_NUM
#define EMB      64
#define NNZ      5000000
#define NROW_ELEMS (NTOT * EMB)   // 16,000,000 floats = 64 MB
#define NCB      977              // ceil(NTOT/256) sub-buckets of 256 rows
#define NSUP     62               // ceil(NTOT/4096) super-buckets of 4096 rows
#define NSB1     1024             // part1 blocks
#define T1       4884             // edges per part1 block (mult of 4)
#define G2       16               // chunks per super-bucket in part2
#define SCAP     6144             // per-sub-bucket LDS cap (mean 5120, +14 sigma)
#define PROTO_ELEMS (2048 * 64)   // 131072 floats per prototype array

typedef unsigned uu2 __attribute__((ext_vector_type(2)));
typedef float    ff2 __attribute__((ext_vector_type(2)));
typedef float    ff4 __attribute__((ext_vector_type(4)));

#if defined(__has_builtin)
#if __has_builtin(__builtin_amdgcn_cvt_pk_f32_fp8) && __has_builtin(__builtin_amdgcn_cvt_pk_fp8_f32)
#define HW_FP8 1
#endif
#endif
#ifndef HW_FP8
#define HW_FP8 0
#endif

// ---------------- fp8 e4m3fn helpers (bit tricks, FTZ below 2^-6) ------------
__device__ __forceinline__ unsigned enc1(float x) {
    unsigned b = __float_as_uint(x);
    unsigned s = (b >> 24) & 0x80u;
    unsigned mag = b & 0x7FFFFFFFu;
    if (mag < 0x3C800000u) return s;                 // < 2^-6 -> zero
    mag += 0x000FFFFFu + ((mag >> 20) & 1u);         // RNE at mantissa bit 20
    unsigned u7 = (mag >> 20) - (120u << 3);         // (e<<3)|m, e = E-120
    return s | (u7 > 0x7Eu ? 0x7Eu : u7);            // clamp to 448 (no NaN)
}
__device__ __forceinline__ float dec1(unsigned u) {
    unsigned em = u & 0x7Fu;
    float f = __uint_as_float((((u & 0x80u) << 24) | (em << 20)) + (120u << 23));
    return (em < 8u) ? 0.f : f;
}

// pack 8 f32 -> 8 fp8 (one uu2)
__device__ __forceinline__ uu2 enc8(const float* a) {
    uu2 w;
#if HW_FP8
    int lo = 0, hi = 0;
    lo = __builtin_amdgcn_cvt_pk_fp8_f32(a[0], a[1], lo, false);
    lo = __builtin_amdgcn_cvt_pk_fp8_f32(a[2], a[3], lo, true);
    hi = __builtin_amdgcn_cvt_pk_fp8_f32(a[4], a[5], hi, false);
    hi = __builtin_amdgcn_cvt_pk_fp8_f32(a[6], a[7], hi, true);
    w.x = (unsigned)lo; w.y = (unsigned)hi;
#else
    w.x = enc1(a[0]) | (enc1(a[1]) << 8) | (enc1(a[2]) << 16) | (enc1(a[3]) << 24);
    w.y = enc1(a[4]) | (enc1(a[5]) << 8) | (enc1(a[6]) << 16) | (enc1(a[7]) << 24);
#endif
    return w;
}

// acc[0..7] += v * fp8x8(u)
__device__ __forceinline__ void acc8q(float* acc, float v, uu2 u) {
#if HW_FP8
    ff2 a = __builtin_amdgcn_cvt_pk_f32_fp8(u.x, false);
    ff2 b = __builtin_amdgcn_cvt_pk_f32_fp8(u.x, true);
    ff2 c = __builtin_amdgcn_cvt_pk_f32_fp8(u.y, false);
    ff2 d = __builtin_amdgcn_cvt_pk_f32_fp8(u.y, true);
    acc[0] += v * a.x; acc[1] += v * a.y; acc[2] += v * b.x; acc[3] += v * b.y;
    acc[4] += v * c.x; acc[5] += v * c.y; acc[6] += v * d.x; acc[7] += v * d.y;
#else
#pragma unroll
    for (int k = 0; k < 4; ++k) acc[k]     += v * dec1((u.x >> (8 * k)) & 0xFFu);
#pragma unroll
    for (int k = 0; k < 4; ++k) acc[4 + k] += v * dec1((u.y >> (8 * k)) & 0xFFu);
#endif
}

// decode 8 fp8 into d[0..7] (for layer-3 assembly)
__device__ __forceinline__ void dec8(float* d, uu2 u) {
#if HW_FP8
    ff2 a = __builtin_amdgcn_cvt_pk_f32_fp8(u.x, false);
    ff2 b = __builtin_amdgcn_cvt_pk_f32_fp8(u.x, true);
    ff2 c = __builtin_amdgcn_cvt_pk_f32_fp8(u.y, false);
    ff2 dd = __builtin_amdgcn_cvt_pk_f32_fp8(u.y, true);
    d[0] = a.x; d[1] = a.y; d[2] = b.x; d[3] = b.y;
    d[4] = c.x; d[5] = c.y; d[6] = dd.x; d[7] = dd.y;
#else
#pragma unroll
    for (int k = 0; k < 4; ++k) d[k]     = dec1((u.x >> (8 * k)) & 0xFFu);
#pragma unroll
    for (int k = 0; k < 4; ++k) d[4 + k] = dec1((u.y >> (8 * k)) & 0xFFu);
#endif
}

#define SCALE_F   32768.0f        // 2^15: layer values stored as x*S
#define OUT_C     (0.25f / 32768.0f)
#define QSCALE    327680.0f       // 16384 / 0.05 (val -> 14-bit fixed)
#define QSTEP     (1.0f / 327680.0f)

// ============================ sub-bucket histogram ===========================
__global__ __launch_bounds__(256) void hist_kernel(const int* __restrict__ rows,
                                                   int* __restrict__ counts) {
    __shared__ int sh[NCB];
    for (int i = threadIdx.x; i < NCB; i += 256) sh[i] = 0;
    __syncthreads();
    int stride = gridDim.x * blockDim.x;
    const int4* rows4 = (const int4*)rows;
    for (int i = blockIdx.x * blockDim.x + threadIdx.x; i < NNZ / 4; i += stride) {
        int4 r = rows4[i];
        atomicAdd(&sh[r.x >> 8], 1);
        atomicAdd(&sh[r.y >> 8], 1);
        atomicAdd(&sh[r.z >> 8], 1);
        atomicAdd(&sh[r.w >> 8], 1);
    }
    __syncthreads();
    for (int i = threadIdx.x; i < NCB; i += 256)
        if (sh[i]) atomicAdd(&counts[i], sh[i]);
}

// exclusive scan over NCB counts -> boffs + bcursor + cursor1; offs[NTOT]=NNZ
__global__ void scan_kernel(const int* __restrict__ counts, int* __restrict__ boffs,
                            int* __restrict__ bcursor, int* __restrict__ cursor1,
                            int* __restrict__ offs) {
    __shared__ int sm[1024];
    int t = threadIdx.x;
    int c = (t < NCB) ? counts[t] : 0;
    sm[t] = c; __syncthreads();
    for (int off = 1; off < 1024; off <<= 1) {
        int v = (t >= off) ? sm[t - off] : 0;
        __syncthreads();
        sm[t] += v;
        __syncthreads();
    }
    if (t < NCB) { boffs[t] = sm[t] - c; bcursor[t] = sm[t] - c; }
    if (t == 1023) { boffs[NCB] = sm[1023]; offs[NTOT] = sm[1023]; }
    if (t < NSUP) cursor1[t] = sm[16 * t] - counts[16 * t];   // = boffs[16t]
}

// ===================== stage-1 partition: 62 super-buckets ===================
// exA word: col (0..17) | lr12 (18..29).  val quantized to 14-bit ushort.
__global__ __launch_bounds__(256) void part1(
        const int* __restrict__ rows, const int* __restrict__ cols,
        const float* __restrict__ vals, int* __restrict__ cursor1,
        int* __restrict__ exA, ushort* __restrict__ valQ) {
    __shared__ int cnt[NSUP];
    __shared__ int base[NSUP];
    int t = threadIdx.x;
    int tb = blockIdx.x * T1;
    int n = NNZ - tb; if (n <= 0) return; if (n > T1) n = T1;   // n % 4 == 0
    if (t < NSUP) cnt[t] = 0;
    __syncthreads();
    for (int i = t * 4; i < n; i += 1024) {          // pass A: count (int4)
        int4 r = *(const int4*)(rows + tb + i);
        atomicAdd(&cnt[r.x >> 12], 1);
        atomicAdd(&cnt[r.y >> 12], 1);
        atomicAdd(&cnt[r.z >> 12], 1);
        atomicAdd(&cnt[r.w >> 12], 1);
    }
    __syncthreads();
    if (t < NSUP) {                                  // claim contiguous runs
        int c = cnt[t];
        base[t] = c ? atomicAdd(&cursor1[t], c) : 0;
        cnt[t] = 0;                                  // reuse as rank cursor
    }
    __syncthreads();
    for (int i = t; i < n; i += 256) {               // pass B: rank + write
        int r = rows[tb + i];
        int s = r >> 12;
        int rank = atomicAdd(&cnt[s], 1);
        int p = base[s] + rank;
        exA[p] = cols[tb + i] | ((r & 4095) << 18);
        int q = (int)(vals[tb + i] * QSCALE + 0.5f);
        valQ[p] = (ushort)(q > 16383 ? 16383 : q);
    }
}

// ============== stage-2 partition: 16 sub-buckets per super-bucket ===========
__global__ __launch_bounds__(256) void part2(
        const int* __restrict__ boffs, int* __restrict__ bcursor,
        const int* __restrict__ exA, const ushort* __restrict__ valQ,
        int* __restrict__ exB, ushort* __restrict__ valQB) {
    __shared__ int cnt[16], base[16], cur[16];
    int b = blockIdx.x;
    int s = b >> 4, k = b & 15;
    int t = threadIdx.x;
    int sb0 = s * 16;
    int nsb = NCB - sb0; if (nsb > 16) nsb = 16;
    int beg = boffs[sb0];
    int end = boffs[sb0 + nsb];
    int n = end - beg;
    int chunk = (n + G2 - 1) / G2;
    int cb = beg + k * chunk;
    int ce = cb + chunk; if (ce > end) ce = end;
    if (cb >= ce) return;
    if (t < 16) cnt[t] = 0;
    __syncthreads();
    for (int i = cb + t; i < ce; i += 256)           // pass A: count
        atomicAdd(&cnt[(exA[i] >> 26) & 15], 1);
    __syncthreads();
    if (t < 16) {
        int c = cnt[t];
        base[t] = c ? atomicAdd(&bcursor[sb0 + t], c) : 0;
        cur[t] = 0;
    }
    __syncthreads();
    for (int i = cb + t; i < ce; i += 256) {         // pass B: rank + write
        int ex = exA[i];
        int j = (ex >> 26) & 15;
        int rank = atomicAdd(&cur[j], 1);
        exB[base[j] + rank] = ex;
        valQB[base[j] + rank] = valQ[i];
    }
}

// ====== per-sub-bucket in-LDS row sort + WITHIN-ROW COLUMN SORT ==============
// Stage bucket in LDS, group by row, then each thread insertion-sorts its own
// row's segment by column (packed word col<<14|q14 -> uint compare == col
// order). Col-sorted rows give the spmm a sliding, L2-resident source window.
// epkF word: col (14..31) | q14 (0..13)
__global__ __launch_bounds__(256) void bucket_sort(const int* __restrict__ boffs,
                                                   const int* __restrict__ exB,
                                                   const ushort* __restrict__ valQB,
                                                   unsigned* __restrict__ epkF,
                                                   int* __restrict__ offs) {
    __shared__ unsigned sw[SCAP];     // 24 KB: staged packed words (input order)
    __shared__ unsigned char slr[SCAP]; // 6 KB: local row per staged edge
    __shared__ unsigned sg[SCAP];     // 24 KB: row-grouped, then col-sorted
    __shared__ int cnt[256];
    __shared__ int lbase[256];
    __shared__ int cur[256];
    int b = blockIdx.x, t = threadIdx.x;
    int beg = boffs[b], end = boffs[b + 1];
    int n = end - beg; if (n > SCAP) n = SCAP;
    cnt[t] = 0;
    __syncthreads();
    for (int i = t; i < n; i += 256) {               // stage + count
        int ex = exB[beg + i];
        unsigned q = valQB[beg + i];
        int lr = (ex >> 18) & 0xFF;
        sw[i] = ((unsigned)(ex & 0x3FFFF) << 14) | q;
        slr[i] = (unsigned char)lr;
        atomicAdd(&cnt[lr], 1);
    }
    __syncthreads();
    int c = cnt[t];
    lbase[t] = c; __syncthreads();
    for (int off = 1; off < 256; off <<= 1) {        // Hillis-Steele inclusive
        int v = (t >= off) ? lbase[t - off] : 0;
        __syncthreads();
        lbase[t] += v;
        __syncthreads();
    }
    int myb = lbase[t] - c;                          // local exclusive base
    cur[t] = myb;
    int r = b * 256 + t;
    if (r < NTOT) offs[r] = beg + myb;
    __syncthreads();
    for (int i = t; i < n; i += 256) {               // scatter into row groups
        int lr = slr[i];
        int p = atomicAdd(&cur[lr], 1);
        sg[p] = sw[i];
    }
    __syncthreads();
    // per-row insertion sort by col (uint compare; col is in high bits)
    for (int i = myb + 1; i < myb + c; ++i) {
        unsigned key = sg[i];
        int j = i - 1;
        while (j >= myb && sg[j] > key) { sg[j + 1] = sg[j]; --j; }
        sg[j + 1] = key;
    }
    __syncthreads();
    for (int i = t; i < n; i += 256)                 // coalesced writeout
        __builtin_nontemporal_store(sg[i], epkF + beg + i);
}

// ======== convert: ego f32 -> fp8 xq (scaled), + f32 pass-throughs ==========
__global__ __launch_bounds__(256) void convert_kernel(
        const float* __restrict__ ue, const float* __restrict__ ie,
        const float* __restrict__ up, const float* __restrict__ ip,
        uu2* __restrict__ xq, float* __restrict__ out) {
    const int NG = NROW_ELEMS / 8;               // 2,000,000 8-elem groups
    int g = blockIdx.x * blockDim.x + threadIdx.x;
    if (g < NG) {
        int base = g * 8;
        const float* src = (base < USER_NUM * EMB) ? ue + base
                                                   : ie + (base - USER_NUM * EMB);
        ff4 a = __builtin_nontemporal_load((const ff4*)src);
        ff4 b = __builtin_nontemporal_load((const ff4*)src + 1);
        ff4* oc = (ff4*)(out + NROW_ELEMS + base);
        __builtin_nontemporal_store(a, oc);
        __builtin_nontemporal_store(b, oc + 1);
        float s[8] = {a.x * SCALE_F, a.y * SCALE_F, a.z * SCALE_F, a.w * SCALE_F,
                      b.x * SCALE_F, b.y * SCALE_F, b.z * SCALE_F, b.w * SCALE_F};
        uu2 w = enc8(s);
        __builtin_nontemporal_store(w, xq + g);
    } else {
        int pj = (g - NG) * 8;
        const float* src;
        float* dst;
        if (pj < PROTO_ELEMS) {
            src = up + pj; dst = out + 2 * NROW_ELEMS + pj;
        } else if (pj < 2 * PROTO_ELEMS) {
            src = ip + (pj - PROTO_ELEMS);
            dst = out + 2 * NROW_ELEMS + pj;
        } else return;
        ff4 a = __builtin_nontemporal_load((const ff4*)src);
        ff4 b = __builtin_nontemporal_load((const ff4*)src + 1);
        __builtin_nontemporal_store(a, (ff4*)dst);
        __builtin_nontemporal_store(b, (ff4*)dst + 1);
    }
}

// ===================== fp8-gather CSR SpMM (no atomics) ======================
// 8 lanes per row; lane l owns dims [8l, 8l+8): one uu2 (8 fp8) per edge.
// Edges are col-sorted within each row -> the whole grid sweeps the source as
// a sliding window that fits per-XCD L2.
// epkF word: col = e>>14, q = e & 0x3FFF.
template <int LAYER>
__global__ __launch_bounds__(256) void spmm_q(
        const uu2* __restrict__ src,         // fp8 gather source, 8 uu2/row
        const int* __restrict__ offs, const unsigned* __restrict__ epk,
        uu2* __restrict__ lq,                // layer output (L1/2)
        const float* __restrict__ ue, const float* __restrict__ ie,   // L3
        const uu2* __restrict__ l1q, const uu2* __restrict__ l2q,     // L3
        float* __restrict__ out) {           // L3
    int t = blockIdx.x * blockDim.x + threadIdx.x;
    int r = t >> 3, l = t & 7;
    if (r >= NTOT) return;
    int beg = offs[r], end = offs[r + 1];
    float acc[8] = {0.f, 0.f, 0.f, 0.f, 0.f, 0.f, 0.f, 0.f};
    int j = beg;
    for (; j + 3 < end; j += 4) {
        unsigned e0 = __builtin_nontemporal_load(epk + j);
        unsigned e1 = __builtin_nontemporal_load(epk + j + 1);
        unsigned e2 = __builtin_nontemporal_load(epk + j + 2);
        unsigned e3 = __builtin_nontemporal_load(epk + j + 3);
        uu2 u0 = src[(e0 >> 14) * 8 + l];
        uu2 u1 = src[(e1 >> 14) * 8 + l];
        uu2 u2 = src[(e2 >> 14) * 8 + l];
        uu2 u3 = src[(e3 >> 14) * 8 + l];
        acc8q(acc, (float)(e0 & 0x3FFFu) * QSTEP, u0);
        acc8q(acc, (float)(e1 & 0x3FFFu) * QSTEP, u1);
        acc8q(acc, (float)(e2 & 0x3FFFu) * QSTEP, u2);
        acc8q(acc, (float)(e3 & 0x3FFFu) * QSTEP, u3);
    }
    for (; j < end; ++j) {
        unsigned e0 = __builtin_nontemporal_load(epk + j);
        uu2 u0 = src[(e0 >> 14) * 8 + l];
        acc8q(acc, (float)(e0 & 0x3FFFu) * QSTEP, u0);
    }
    int idx = r * 8 + l;
    if (LAYER == 1 || LAYER == 2) {
        uu2 w = enc8(acc);
        __builtin_nontemporal_store(w, lq + idx);
    } else {
        int base = r * EMB + l * 8;
        const float* ep = (r < USER_NUM) ? ue + base
                                         : ie + (base - USER_NUM * EMB);
        ff4 ea = __builtin_nontemporal_load((const ff4*)ep);
        ff4 eb = __builtin_nontemporal_load((const ff4*)ep + 1);
        uu2 u1 = __builtin_nontemporal_load(l1q + idx);
        uu2 u2 = __builtin_nontemporal_load(l2q + idx);
        float d1[8], d2[8];
        dec8(d1, u1);
        dec8(d2, u2);
        ff4 o0, o1;
        o0.x = ea.x * 0.25f + (d1[0] + d2[0] + acc[0]) * OUT_C;
        o0.y = ea.y * 0.25f + (d1[1] + d2[1] + acc[1]) * OUT_C;
        o0.z = ea.z * 0.25f + (d1[2] + d2[2] + acc[2]) * OUT_C;
        o0.w = ea.w * 0.25f + (d1[3] + d2[3] + acc[3]) * OUT_C;
        o1.x = eb.x * 0.25f + (d1[4] + d2[4] + acc[4]) * OUT_C;
        o1.y = eb.y * 0.25f + (d1[5] + d2[5] + acc[5]) * OUT_C;
        o1.z = eb.z * 0.25f + (d1[6] + d2[6] + acc[6]) * OUT_C;
        o1.w = eb.w * 0.25f + (d1[7] + d2[7] + acc[7]) * OUT_C;
        __builtin_nontemporal_store(o0, (ff4*)(out + base));
        __builtin_nontemporal_store(o1, (ff4*)(out + base) + 1);
    }
}

// =============================================================================
extern "C" void kernel_launch(void* const* d_in, const int* in_sizes, int n_in,
                              void* d_out, int out_size, void* d_ws, size_t ws_size,
                              hipStream_t stream) {
    const float* ue   = (const float*)d_in[0];
    const float* ie   = (const float*)d_in[1];
    const float* up   = (const float*)d_in[2];
    const float* ip   = (const float*)d_in[3];
    const float* vals = (const float*)d_in[4];
    const int*   rows = (const int*)d_in[5];
    const int*   cols = (const int*)d_in[6];
    float* out = (float*)d_out;

    // ws layout (4-byte units):
    //   [0, 5M)          exA    : stage-1 keys (20 MB)
    //   [5M, 10M)        exB    : stage-2 keys (20 MB)
    //   [10M, 11.25M)    valQ   : 5M ushort (10 MB)
    //   [11.25M, 12.5M)  valQB  : 5M ushort (10 MB)
    //   [12.5M, 17.5M)   epkF   : 5M packed edges (20 MB)
    //   [17.5M, 21.5M)   xq     : fp8 ego (16 MB), ALIASED as l2q after spmm1
    //   [21.5M, 25.5M)   l1q    : fp8 layer-1 (16 MB)
    //   26,000,000       offs   : NTOT+1 row offsets
    //   26,250,112       boffs  : NCB+1
    //   26,252,000       bcursor: NCB
    //   26,253,000       bcounts: NCB
    //   26,254,000       cursor1: NSUP
    int*      exA    = (int*)d_ws;
    int*      exB    = (int*)d_ws + 5000000;
    ushort*   valQ   = (ushort*)((int*)d_ws + 10000000);
    ushort*   valQB  = (ushort*)((int*)d_ws + 11250000);
    unsigned* epkF   = (unsigned*)((int*)d_ws + 12500000);
    uu2*      xq     = (uu2*)((int*)d_ws + 17500000);
    uu2*      l1q    = (uu2*)((int*)d_ws + 21500000);
    int*      offs   = (int*)d_ws + 26000000;
    int*      boffs  = (int*)d_ws + 26250112;
    int*      bcursor= (int*)d_ws + 26252000;
    int*      bcounts= (int*)d_ws + 26253000;
    int*      cursor1= (int*)d_ws + 26254000;
    uu2*      l2q    = xq;                           // xq dead after spmm1

    const int sgrid = (NTOT * 8 + 255) / 256;        // 7813
    const int cgrid = (NROW_ELEMS / 8 + 2 * PROTO_ELEMS / 8 + 255) / 256;

    // ---- build row-sorted, within-row col-sorted compressed CSR ----
    hipMemsetAsync(bcounts, 0, NCB * sizeof(int), stream);
    hist_kernel<<<256, 256, 0, stream>>>(rows, bcounts);
    scan_kernel<<<1, 1024, 0, stream>>>(bcounts, boffs, bcursor, cursor1, offs);
    part1      <<<NSB1, 256, 0, stream>>>(rows, cols, vals, cursor1, exA, valQ);
    part2      <<<NSUP * G2, 256, 0, stream>>>(boffs, bcursor, exA, valQ, exB, valQB);
    bucket_sort<<<NCB, 256, 0, stream>>>(boffs, exB, valQB, epkF, offs);

    // ---- convert ego to scaled fp8 + all f32 pass-through copies ----
    convert_kernel<<<cgrid, 256, 0, stream>>>(ue, ie, up, ip, xq, out);

    // ---- 3 fp8-gather SpMM layers; f32 assembly in layer 3 ----
    spmm_q<1><<<sgrid, 256, 0, stream>>>(xq,  offs, epkF, l1q,
                                         nullptr, nullptr, nullptr, nullptr, nullptr);
    spmm_q<2><<<sgrid, 256, 0, stream>>>(l1q, offs, epkF, l2q,
                                         nullptr, nullptr, nullptr, nullptr, nullptr);
    spmm_q<3><<<sgrid, 256, 0, stream>>>(l2q, offs, epkF, nullptr,
                                         ue, ie, l1q, l2q, out);
}

// Round 12
// 455.925 us; speedup vs baseline: 1.2526x; 1.2526x over previous
//
#include <hip/hip_runtime.h>

#define USER_NUM 100000
#define ITEM_NUM 150000
#define NTOT     250000           // USER_NUM + ITEM_NUM
#define EMB      64
#define NNZ      5000000
#define NROW_ELEMS (NTOT * EMB)   // 16,000,000 floats = 64 MB
#define NCB      977              // ceil(NTOT/256) sub-buckets of 256 rows
#define NSUP     62               // ceil(NTOT/4096) super-buckets of 4096 rows
#define NSB1     1024             // part1 blocks
#define T1       4884             // edges per part1 block (mult of 4)
#define G2       16               // chunks per super-bucket in part2
#define SCAP     6144             // per-sub-bucket LDS cap (mean 5120, +14 sigma)
#define PROTO_ELEMS (2048 * 64)   // 131072 floats per prototype array

typedef unsigned uu2 __attribute__((ext_vector_type(2)));
typedef float    ff2 __attribute__((ext_vector_type(2)));
typedef float    ff4 __attribute__((ext_vector_type(4)));

#if defined(__has_builtin)
#if __has_builtin(__builtin_amdgcn_cvt_pk_f32_fp8) && __has_builtin(__builtin_amdgcn_cvt_pk_fp8_f32)
#define HW_FP8 1
#endif
#endif
#ifndef HW_FP8
#define HW_FP8 0
#endif

// ---------------- fp8 e4m3fn helpers (bit tricks, FTZ below 2^-6) ------------
__device__ __forceinline__ unsigned enc1(float x) {
    unsigned b = __float_as_uint(x);
    unsigned s = (b >> 24) & 0x80u;
    unsigned mag = b & 0x7FFFFFFFu;
    if (mag < 0x3C800000u) return s;                 // < 2^-6 -> zero
    mag += 0x000FFFFFu + ((mag >> 20) & 1u);         // RNE at mantissa bit 20
    unsigned u7 = (mag >> 20) - (120u << 3);         // (e<<3)|m, e = E-120
    return s | (u7 > 0x7Eu ? 0x7Eu : u7);            // clamp to 448 (no NaN)
}
__device__ __forceinline__ float dec1(unsigned u) {
    unsigned em = u & 0x7Fu;
    float f = __uint_as_float((((u & 0x80u) << 24) | (em << 20)) + (120u << 23));
    return (em < 8u) ? 0.f : f;
}

// pack 8 f32 -> 8 fp8 (one uu2)
__device__ __forceinline__ uu2 enc8(const float* a) {
    uu2 w;
#if HW_FP8
    int lo = 0, hi = 0;
    lo = __builtin_amdgcn_cvt_pk_fp8_f32(a[0], a[1], lo, false);
    lo = __builtin_amdgcn_cvt_pk_fp8_f32(a[2], a[3], lo, true);
    hi = __builtin_amdgcn_cvt_pk_fp8_f32(a[4], a[5], hi, false);
    hi = __builtin_amdgcn_cvt_pk_fp8_f32(a[6], a[7], hi, true);
    w.x = (unsigned)lo; w.y = (unsigned)hi;
#else
    w.x = enc1(a[0]) | (enc1(a[1]) << 8) | (enc1(a[2]) << 16) | (enc1(a[3]) << 24);
    w.y = enc1(a[4]) | (enc1(a[5]) << 8) | (enc1(a[6]) << 16) | (enc1(a[7]) << 24);
#endif
    return w;
}

// acc[0..7] += v * fp8x8(u)
__device__ __forceinline__ void acc8q(float* acc, float v, uu2 u) {
#if HW_FP8
    ff2 a = __builtin_amdgcn_cvt_pk_f32_fp8(u.x, false);
    ff2 b = __builtin_amdgcn_cvt_pk_f32_fp8(u.x, true);
    ff2 c = __builtin_amdgcn_cvt_pk_f32_fp8(u.y, false);
    ff2 d = __builtin_amdgcn_cvt_pk_f32_fp8(u.y, true);
    acc[0] += v * a.x; acc[1] += v * a.y; acc[2] += v * b.x; acc[3] += v * b.y;
    acc[4] += v * c.x; acc[5] += v * c.y; acc[6] += v * d.x; acc[7] += v * d.y;
#else
#pragma unroll
    for (int k = 0; k < 4; ++k) acc[k]     += v * dec1((u.x >> (8 * k)) & 0xFFu);
#pragma unroll
    for (int k = 0; k < 4; ++k) acc[4 + k] += v * dec1((u.y >> (8 * k)) & 0xFFu);
#endif
}

// decode 8 fp8 into d[0..7] (for layer-3 assembly)
__device__ __forceinline__ void dec8(float* d, uu2 u) {
#if HW_FP8
    ff2 a = __builtin_amdgcn_cvt_pk_f32_fp8(u.x, false);
    ff2 b = __builtin_amdgcn_cvt_pk_f32_fp8(u.x, true);
    ff2 c = __builtin_amdgcn_cvt_pk_f32_fp8(u.y, false);
    ff2 dd = __builtin_amdgcn_cvt_pk_f32_fp8(u.y, true);
    d[0] = a.x; d[1] = a.y; d[2] = b.x; d[3] = b.y;
    d[4] = c.x; d[5] = c.y; d[6] = dd.x; d[7] = dd.y;
#else
#pragma unroll
    for (int k = 0; k < 4; ++k) d[k]     = dec1((u.x >> (8 * k)) & 0xFFu);
#pragma unroll
    for (int k = 0; k < 4; ++k) d[4 + k] = dec1((u.y >> (8 * k)) & 0xFFu);
#endif
}

#define SCALE_F   32768.0f        // 2^15: layer values stored as x*S
#define OUT_C     (0.25f / 32768.0f)
#define QSCALE    327680.0f       // 16384 / 0.05 (val -> 14-bit fixed)
#define QSTEP     (1.0f / 327680.0f)

// ============================ sub-bucket histogram ===========================
__global__ __launch_bounds__(256) void hist_kernel(const int* __restrict__ rows,
                                                   int* __restrict__ counts) {
    __shared__ int sh[NCB];
    for (int i = threadIdx.x; i < NCB; i += 256) sh[i] = 0;
    __syncthreads();
    int stride = gridDim.x * blockDim.x;
    const int4* rows4 = (const int4*)rows;
    for (int i = blockIdx.x * blockDim.x + threadIdx.x; i < NNZ / 4; i += stride) {
        int4 r = rows4[i];
        atomicAdd(&sh[r.x >> 8], 1);
        atomicAdd(&sh[r.y >> 8], 1);
        atomicAdd(&sh[r.z >> 8], 1);
        atomicAdd(&sh[r.w >> 8], 1);
    }
    __syncthreads();
    for (int i = threadIdx.x; i < NCB; i += 256)
        if (sh[i]) atomicAdd(&counts[i], sh[i]);
}

// exclusive scan over NCB counts -> boffs + bcursor + cursor1; offs[NTOT]=NNZ
__global__ void scan_kernel(const int* __restrict__ counts, int* __restrict__ boffs,
                            int* __restrict__ bcursor, int* __restrict__ cursor1,
                            int* __restrict__ offs) {
    __shared__ int sm[1024];
    int t = threadIdx.x;
    int c = (t < NCB) ? counts[t] : 0;
    sm[t] = c; __syncthreads();
    for (int off = 1; off < 1024; off <<= 1) {
        int v = (t >= off) ? sm[t - off] : 0;
        __syncthreads();
        sm[t] += v;
        __syncthreads();
    }
    if (t < NCB) { boffs[t] = sm[t] - c; bcursor[t] = sm[t] - c; }
    if (t == 1023) { boffs[NCB] = sm[1023]; offs[NTOT] = sm[1023]; }
    if (t < NSUP) cursor1[t] = sm[16 * t] - counts[16 * t];   // = boffs[16t]
}

// ===================== stage-1 partition: 62 super-buckets ===================
// exA word: col (0..17) | lr12 (18..29).  val quantized to 14-bit ushort.
__global__ __launch_bounds__(256) void part1(
        const int* __restrict__ rows, const int* __restrict__ cols,
        const float* __restrict__ vals, int* __restrict__ cursor1,
        int* __restrict__ exA, ushort* __restrict__ valQ) {
    __shared__ int cnt[NSUP];
    __shared__ int base[NSUP];
    int t = threadIdx.x;
    int tb = blockIdx.x * T1;
    int n = NNZ - tb; if (n <= 0) return; if (n > T1) n = T1;   // n % 4 == 0
    if (t < NSUP) cnt[t] = 0;
    __syncthreads();
    for (int i = t * 4; i < n; i += 1024) {          // pass A: count (int4)
        int4 r = *(const int4*)(rows + tb + i);
        atomicAdd(&cnt[r.x >> 12], 1);
        atomicAdd(&cnt[r.y >> 12], 1);
        atomicAdd(&cnt[r.z >> 12], 1);
        atomicAdd(&cnt[r.w >> 12], 1);
    }
    __syncthreads();
    if (t < NSUP) {                                  // claim contiguous runs
        int c = cnt[t];
        base[t] = c ? atomicAdd(&cursor1[t], c) : 0;
        cnt[t] = 0;                                  // reuse as rank cursor
    }
    __syncthreads();
    for (int i = t; i < n; i += 256) {               // pass B: rank + write
        int r = rows[tb + i];
        int s = r >> 12;
        int rank = atomicAdd(&cnt[s], 1);
        int p = base[s] + rank;
        exA[p] = cols[tb + i] | ((r & 4095) << 18);
        int q = (int)(vals[tb + i] * QSCALE + 0.5f);
        valQ[p] = (ushort)(q > 16383 ? 16383 : q);
    }
}

// ============== stage-2 partition: 16 sub-buckets per super-bucket ===========
__global__ __launch_bounds__(256) void part2(
        const int* __restrict__ boffs, int* __restrict__ bcursor,
        const int* __restrict__ exA, const ushort* __restrict__ valQ,
        int* __restrict__ exB, ushort* __restrict__ valQB) {
    __shared__ int cnt[16], base[16], cur[16];
    int b = blockIdx.x;
    int s = b >> 4, k = b & 15;
    int t = threadIdx.x;
    int sb0 = s * 16;
    int nsb = NCB - sb0; if (nsb > 16) nsb = 16;
    int beg = boffs[sb0];
    int end = boffs[sb0 + nsb];
    int n = end - beg;
    int chunk = (n + G2 - 1) / G2;
    int cb = beg + k * chunk;
    int ce = cb + chunk; if (ce > end) ce = end;
    if (cb >= ce) return;
    if (t < 16) cnt[t] = 0;
    __syncthreads();
    for (int i = cb + t; i < ce; i += 256)           // pass A: count
        atomicAdd(&cnt[(exA[i] >> 26) & 15], 1);
    __syncthreads();
    if (t < 16) {
        int c = cnt[t];
        base[t] = c ? atomicAdd(&bcursor[sb0 + t], c) : 0;
        cur[t] = 0;
    }
    __syncthreads();
    for (int i = cb + t; i < ce; i += 256) {         // pass B: rank + write
        int ex = exA[i];
        int j = (ex >> 26) & 15;
        int rank = atomicAdd(&cur[j], 1);
        exB[base[j] + rank] = ex;
        valQB[base[j] + rank] = valQ[i];
    }
}

// ============== per-sub-bucket in-LDS row sort -> final packed epk ===========
// epkF word: col (0..17) | q14 (18..31)
__global__ __launch_bounds__(256) void bucket_sort(const int* __restrict__ boffs,
                                                   const int* __restrict__ exB,
                                                   const ushort* __restrict__ valQB,
                                                   unsigned* __restrict__ epkF,
                                                   int* __restrict__ offs) {
    __shared__ int sx[SCAP];          // 24 KB
    __shared__ ushort sv[SCAP];       // 12 KB
    __shared__ int cnt[256];
    __shared__ int base[256];
    __shared__ int cur[256];
    int b = blockIdx.x, t = threadIdx.x;
    int beg = boffs[b], end = boffs[b + 1];
    int n = end - beg; if (n > SCAP) n = SCAP;
    cnt[t] = 0;
    __syncthreads();
    for (int i = t; i < n; i += 256) {
        int ex = exB[beg + i];
        sx[i] = ex;
        sv[i] = valQB[beg + i];
        atomicAdd(&cnt[(ex >> 18) & 0xFF], 1);
    }
    __syncthreads();
    int c = cnt[t];
    base[t] = c; __syncthreads();
    for (int off = 1; off < 256; off <<= 1) {     // Hillis-Steele inclusive
        int v = (t >= off) ? base[t - off] : 0;
        __syncthreads();
        base[t] += v;
        __syncthreads();
    }
    int mybase = beg + base[t] - c;
    cur[t] = mybase;
    int r = b * 256 + t;
    if (r < NTOT) offs[r] = mybase;
    __syncthreads();
    for (int i = t; i < n; i += 256) {
        int ex = sx[i];
        int lr = (ex >> 18) & 0xFF;
        int p = atomicAdd(&cur[lr], 1);
        epkF[p] = ((unsigned)ex & 0x3FFFFu) | ((unsigned)sv[i] << 18);
    }
}

// ======== convert: ego f32 -> fp8 xq (scaled), + f32 pass-throughs ==========
__global__ __launch_bounds__(256) void convert_kernel(
        const float* __restrict__ ue, const float* __restrict__ ie,
        const float* __restrict__ up, const float* __restrict__ ip,
        uu2* __restrict__ xq, float* __restrict__ out) {
    const int NG = NROW_ELEMS / 8;               // 2,000,000 8-elem groups
    int g = blockIdx.x * blockDim.x + threadIdx.x;
    if (g < NG) {
        int base = g * 8;
        const float* src = (base < USER_NUM * EMB) ? ue + base
                                                   : ie + (base - USER_NUM * EMB);
        ff4 a = __builtin_nontemporal_load((const ff4*)src);
        ff4 b = __builtin_nontemporal_load((const ff4*)src + 1);
        ff4* oc = (ff4*)(out + NROW_ELEMS + base);
        __builtin_nontemporal_store(a, oc);
        __builtin_nontemporal_store(b, oc + 1);
        float s[8] = {a.x * SCALE_F, a.y * SCALE_F, a.z * SCALE_F, a.w * SCALE_F,
                      b.x * SCALE_F, b.y * SCALE_F, b.z * SCALE_F, b.w * SCALE_F};
        uu2 w = enc8(s);
        __builtin_nontemporal_store(w, xq + g);
    } else {
        int pj = (g - NG) * 8;
        const float* src;
        float* dst;
        if (pj < PROTO_ELEMS) {
            src = up + pj; dst = out + 2 * NROW_ELEMS + pj;
        } else if (pj < 2 * PROTO_ELEMS) {
            src = ip + (pj - PROTO_ELEMS);
            dst = out + 2 * NROW_ELEMS + pj;
        } else return;
        ff4 a = __builtin_nontemporal_load((const ff4*)src);
        ff4 b = __builtin_nontemporal_load((const ff4*)src + 1);
        __builtin_nontemporal_store(a, (ff4*)dst);
        __builtin_nontemporal_store(b, (ff4*)dst + 1);
    }
}

// ===================== fp8-gather CSR SpMM (no atomics) ======================
// 8 lanes per row; lane l owns dims [8l, 8l+8): one uu2 (8 fp8) per edge.
// 8-deep software pipeline: load 8 edge words, issue 8 independent gathers,
// only then run the dependent FMA chains (MLP ~8 lines in flight per wave).
template <int LAYER>
__global__ __launch_bounds__(256) void spmm_q(
        const uu2* __restrict__ src,         // fp8 gather source, 8 uu2/row
        const int* __restrict__ offs, const unsigned* __restrict__ epk,
        uu2* __restrict__ lq,                // layer output (L1/2)
        const float* __restrict__ ue, const float* __restrict__ ie,   // L3
        const uu2* __restrict__ l1q, const uu2* __restrict__ l2q,     // L3
        float* __restrict__ out) {           // L3
    int t = blockIdx.x * blockDim.x + threadIdx.x;
    int r = t >> 3, l = t & 7;
    if (r >= NTOT) return;
    int beg = offs[r], end = offs[r + 1];
    float acc[8] = {0.f, 0.f, 0.f, 0.f, 0.f, 0.f, 0.f, 0.f};
    int j = beg;
    for (; j + 7 < end; j += 8) {
        unsigned e[8];
#pragma unroll
        for (int k = 0; k < 8; ++k)
            e[k] = __builtin_nontemporal_load(epk + j + k);
        uu2 u[8];
#pragma unroll
        for (int k = 0; k < 8; ++k)
            u[k] = src[(e[k] & 0x3FFFFu) * 8 + l];
#pragma unroll
        for (int k = 0; k < 8; ++k)
            acc8q(acc, (float)(e[k] >> 18) * QSTEP, u[k]);
    }
    if (j + 3 < end) {
        unsigned e[4];
#pragma unroll
        for (int k = 0; k < 4; ++k)
            e[k] = __builtin_nontemporal_load(epk + j + k);
        uu2 u[4];
#pragma unroll
        for (int k = 0; k < 4; ++k)
            u[k] = src[(e[k] & 0x3FFFFu) * 8 + l];
#pragma unroll
        for (int k = 0; k < 4; ++k)
            acc8q(acc, (float)(e[k] >> 18) * QSTEP, u[k]);
        j += 4;
    }
    for (; j < end; ++j) {
        unsigned e0 = __builtin_nontemporal_load(epk + j);
        uu2 u0 = src[(e0 & 0x3FFFFu) * 8 + l];
        acc8q(acc, (float)(e0 >> 18) * QSTEP, u0);
    }
    int idx = r * 8 + l;
    if (LAYER == 1 || LAYER == 2) {
        uu2 w = enc8(acc);
        __builtin_nontemporal_store(w, lq + idx);
    } else {
        int base = r * EMB + l * 8;
        const float* ep = (r < USER_NUM) ? ue + base
                                         : ie + (base - USER_NUM * EMB);
        ff4 ea = __builtin_nontemporal_load((const ff4*)ep);
        ff4 eb = __builtin_nontemporal_load((const ff4*)ep + 1);
        uu2 u1 = __builtin_nontemporal_load(l1q + idx);
        uu2 u2 = __builtin_nontemporal_load(l2q + idx);
        float d1[8], d2[8];
        dec8(d1, u1);
        dec8(d2, u2);
        ff4 o0, o1;
        o0.x = ea.x * 0.25f + (d1[0] + d2[0] + acc[0]) * OUT_C;
        o0.y = ea.y * 0.25f + (d1[1] + d2[1] + acc[1]) * OUT_C;
        o0.z = ea.z * 0.25f + (d1[2] + d2[2] + acc[2]) * OUT_C;
        o0.w = ea.w * 0.25f + (d1[3] + d2[3] + acc[3]) * OUT_C;
        o1.x = eb.x * 0.25f + (d1[4] + d2[4] + acc[4]) * OUT_C;
        o1.y = eb.y * 0.25f + (d1[5] + d2[5] + acc[5]) * OUT_C;
        o1.z = eb.z * 0.25f + (d1[6] + d2[6] + acc[6]) * OUT_C;
        o1.w = eb.w * 0.25f + (d1[7] + d2[7] + acc[7]) * OUT_C;
        __builtin_nontemporal_store(o0, (ff4*)(out + base));
        __builtin_nontemporal_store(o1, (ff4*)(out + base) + 1);
    }
}

// =============================================================================
extern "C" void kernel_launch(void* const* d_in, const int* in_sizes, int n_in,
                              void* d_out, int out_size, void* d_ws, size_t ws_size,
                              hipStream_t stream) {
    const float* ue   = (const float*)d_in[0];
    const float* ie   = (const float*)d_in[1];
    const float* up   = (const float*)d_in[2];
    const float* ip   = (const float*)d_in[3];
    const float* vals = (const float*)d_in[4];
    const int*   rows = (const int*)d_in[5];
    const int*   cols = (const int*)d_in[6];
    float* out = (float*)d_out;

    // ws layout (4-byte units):
    //   [0, 5M)          exA    : stage-1 keys (20 MB)
    //   [5M, 10M)        exB    : stage-2 keys (20 MB)
    //   [10M, 11.25M)    valQ   : 5M ushort (10 MB)
    //   [11.25M, 12.5M)  valQB  : 5M ushort (10 MB)
    //   [12.5M, 17.5M)   epkF   : 5M packed edges (20 MB)
    //   [17.5M, 21.5M)   xq     : fp8 ego (16 MB), ALIASED as l2q after spmm1
    //   [21.5M, 25.5M)   l1q    : fp8 layer-1 (16 MB)
    //   26,000,000       offs   : NTOT+1 row offsets
    //   26,250,112       boffs  : NCB+1
    //   26,252,000       bcursor: NCB
    //   26,253,000       bcounts: NCB
    //   26,254,000       cursor1: NSUP
    int*      exA    = (int*)d_ws;
    int*      exB    = (int*)d_ws + 5000000;
    ushort*   valQ   = (ushort*)((int*)d_ws + 10000000);
    ushort*   valQB  = (ushort*)((int*)d_ws + 11250000);
    unsigned* epkF   = (unsigned*)((int*)d_ws + 12500000);
    uu2*      xq     = (uu2*)((int*)d_ws + 17500000);
    uu2*      l1q    = (uu2*)((int*)d_ws + 21500000);
    int*      offs   = (int*)d_ws + 26000000;
    int*      boffs  = (int*)d_ws + 26250112;
    int*      bcursor= (int*)d_ws + 26252000;
    int*      bcounts= (int*)d_ws + 26253000;
    int*      cursor1= (int*)d_ws + 26254000;
    uu2*      l2q    = xq;                           // xq dead after spmm1

    const int sgrid = (NTOT * 8 + 255) / 256;        // 7813
    const int cgrid = (NROW_ELEMS / 8 + 2 * PROTO_ELEMS / 8 + 255) / 256;

    // ---- build row-sorted compressed CSR ----
    hipMemsetAsync(bcounts, 0, NCB * sizeof(int), stream);
    hist_kernel<<<256, 256, 0, stream>>>(rows, bcounts);
    scan_kernel<<<1, 1024, 0, stream>>>(bcounts, boffs, bcursor, cursor1, offs);
    part1      <<<NSB1, 256, 0, stream>>>(rows, cols, vals, cursor1, exA, valQ);
    part2      <<<NSUP * G2, 256, 0, stream>>>(boffs, bcursor, exA, valQ, exB, valQB);
    bucket_sort<<<NCB, 256, 0, stream>>>(boffs, exB, valQB, epkF, offs);

    // ---- convert ego to scaled fp8 + all f32 pass-through copies ----
    convert_kernel<<<cgrid, 256, 0, stream>>>(ue, ie, up, ip, xq, out);

    // ---- 3 fp8-gather SpMM layers; f32 assembly in layer 3 ----
    spmm_q<1><<<sgrid, 256, 0, stream>>>(xq,  offs, epkF, l1q,
                                         nullptr, nullptr, nullptr, nullptr, nullptr);
    spmm_q<2><<<sgrid, 256, 0, stream>>>(l1q, offs, epkF, l2q,
                                         nullptr, nullptr, nullptr, nullptr, nullptr);
    spmm_q<3><<<sgrid, 256, 0, stream>>>(l2q, offs, epkF, nullptr,
                                         ue, ie, l1q, l2q, out);
}

// Round 13
// 452.104 us; speedup vs baseline: 1.2632x; 1.0085x over previous
//
#include <hip/hip_runtime.h>

#define USER_NUM 100000
#define ITEM_NUM 150000
#define NTOT     250000           // USER_NUM + ITEM_NUM
#define EMB      64
#define NNZ      5000000
#define NROW_ELEMS (NTOT * EMB)   // 16,000,000 floats = 64 MB
#define NCB      977              // ceil(NTOT/256) sub-buckets of 256 rows
#define NSUP     62               // ceil(NTOT/4096) super-buckets of 4096 rows
#define NSB1     1024             // part1 blocks
#define T1       4884             // edges per part1 block (mult of 4)
#define G2       16               // chunks per super-bucket in part2
#define SCAP     6144             // per-sub-bucket LDS cap (mean 5120, +14 sigma)
#define SCAP2    5504             // part2 chunk LDS cap (mean 5040, +25 sigma)
#define PROTO_ELEMS (2048 * 64)   // 131072 floats per prototype array

typedef unsigned uu2 __attribute__((ext_vector_type(2)));
typedef float    ff2 __attribute__((ext_vector_type(2)));
typedef float    ff4 __attribute__((ext_vector_type(4)));

#if defined(__has_builtin)
#if __has_builtin(__builtin_amdgcn_cvt_pk_f32_fp8) && __has_builtin(__builtin_amdgcn_cvt_pk_fp8_f32)
#define HW_FP8 1
#endif
#endif
#ifndef HW_FP8
#define HW_FP8 0
#endif

// ---------------- fp8 e4m3fn helpers (bit tricks, FTZ below 2^-6) ------------
__device__ __forceinline__ unsigned enc1(float x) {
    unsigned b = __float_as_uint(x);
    unsigned s = (b >> 24) & 0x80u;
    unsigned mag = b & 0x7FFFFFFFu;
    if (mag < 0x3C800000u) return s;                 // < 2^-6 -> zero
    mag += 0x000FFFFFu + ((mag >> 20) & 1u);         // RNE at mantissa bit 20
    unsigned u7 = (mag >> 20) - (120u << 3);         // (e<<3)|m, e = E-120
    return s | (u7 > 0x7Eu ? 0x7Eu : u7);            // clamp to 448 (no NaN)
}
__device__ __forceinline__ float dec1(unsigned u) {
    unsigned em = u & 0x7Fu;
    float f = __uint_as_float((((u & 0x80u) << 24) | (em << 20)) + (120u << 23));
    return (em < 8u) ? 0.f : f;
}

// pack 8 f32 -> 8 fp8 (one uu2)
__device__ __forceinline__ uu2 enc8(const float* a) {
    uu2 w;
#if HW_FP8
    int lo = 0, hi = 0;
    lo = __builtin_amdgcn_cvt_pk_fp8_f32(a[0], a[1], lo, false);
    lo = __builtin_amdgcn_cvt_pk_fp8_f32(a[2], a[3], lo, true);
    hi = __builtin_amdgcn_cvt_pk_fp8_f32(a[4], a[5], hi, false);
    hi = __builtin_amdgcn_cvt_pk_fp8_f32(a[6], a[7], hi, true);
    w.x = (unsigned)lo; w.y = (unsigned)hi;
#else
    w.x = enc1(a[0]) | (enc1(a[1]) << 8) | (enc1(a[2]) << 16) | (enc1(a[3]) << 24);
    w.y = enc1(a[4]) | (enc1(a[5]) << 8) | (enc1(a[6]) << 16) | (enc1(a[7]) << 24);
#endif
    return w;
}

// acc[0..7] += v * fp8x8(u)
__device__ __forceinline__ void acc8q(float* acc, float v, uu2 u) {
#if HW_FP8
    ff2 a = __builtin_amdgcn_cvt_pk_f32_fp8(u.x, false);
    ff2 b = __builtin_amdgcn_cvt_pk_f32_fp8(u.x, true);
    ff2 c = __builtin_amdgcn_cvt_pk_f32_fp8(u.y, false);
    ff2 d = __builtin_amdgcn_cvt_pk_f32_fp8(u.y, true);
    acc[0] += v * a.x; acc[1] += v * a.y; acc[2] += v * b.x; acc[3] += v * b.y;
    acc[4] += v * c.x; acc[5] += v * c.y; acc[6] += v * d.x; acc[7] += v * d.y;
#else
#pragma unroll
    for (int k = 0; k < 4; ++k) acc[k]     += v * dec1((u.x >> (8 * k)) & 0xFFu);
#pragma unroll
    for (int k = 0; k < 4; ++k) acc[4 + k] += v * dec1((u.y >> (8 * k)) & 0xFFu);
#endif
}

// decode 8 fp8 into d[0..7] (for layer-3 assembly)
__device__ __forceinline__ void dec8(float* d, uu2 u) {
#if HW_FP8
    ff2 a = __builtin_amdgcn_cvt_pk_f32_fp8(u.x, false);
    ff2 b = __builtin_amdgcn_cvt_pk_f32_fp8(u.x, true);
    ff2 c = __builtin_amdgcn_cvt_pk_f32_fp8(u.y, false);
    ff2 dd = __builtin_amdgcn_cvt_pk_f32_fp8(u.y, true);
    d[0] = a.x; d[1] = a.y; d[2] = b.x; d[3] = b.y;
    d[4] = c.x; d[5] = c.y; d[6] = dd.x; d[7] = dd.y;
#else
#pragma unroll
    for (int k = 0; k < 4; ++k) d[k]     = dec1((u.x >> (8 * k)) & 0xFFu);
#pragma unroll
    for (int k = 0; k < 4; ++k) d[4 + k] = dec1((u.y >> (8 * k)) & 0xFFu);
#endif
}

#define SCALE_F   32768.0f        // 2^15: layer values stored as x*S
#define OUT_C     (0.25f / 32768.0f)
#define QSCALE    327680.0f       // 16384 / 0.05 (val -> 14-bit fixed)
#define QSTEP     (1.0f / 327680.0f)

// ============================ sub-bucket histogram ===========================
__global__ __launch_bounds__(256) void hist_kernel(const int* __restrict__ rows,
                                                   int* __restrict__ counts) {
    __shared__ int sh[NCB];
    for (int i = threadIdx.x; i < NCB; i += 256) sh[i] = 0;
    __syncthreads();
    int stride = gridDim.x * blockDim.x;
    const int4* rows4 = (const int4*)rows;
    for (int i = blockIdx.x * blockDim.x + threadIdx.x; i < NNZ / 4; i += stride) {
        int4 r = rows4[i];
        atomicAdd(&sh[r.x >> 8], 1);
        atomicAdd(&sh[r.y >> 8], 1);
        atomicAdd(&sh[r.z >> 8], 1);
        atomicAdd(&sh[r.w >> 8], 1);
    }
    __syncthreads();
    for (int i = threadIdx.x; i < NCB; i += 256)
        if (sh[i]) atomicAdd(&counts[i], sh[i]);
}

// exclusive scan over NCB counts -> boffs + bcursor + cursor1; offs[NTOT]=NNZ
__global__ void scan_kernel(const int* __restrict__ counts, int* __restrict__ boffs,
                            int* __restrict__ bcursor, int* __restrict__ cursor1,
                            int* __restrict__ offs) {
    __shared__ int sm[1024];
    int t = threadIdx.x;
    int c = (t < NCB) ? counts[t] : 0;
    sm[t] = c; __syncthreads();
    for (int off = 1; off < 1024; off <<= 1) {
        int v = (t >= off) ? sm[t - off] : 0;
        __syncthreads();
        sm[t] += v;
        __syncthreads();
    }
    if (t < NCB) { boffs[t] = sm[t] - c; bcursor[t] = sm[t] - c; }
    if (t == 1023) { boffs[NCB] = sm[1023]; offs[NTOT] = sm[1023]; }
    if (t < NSUP) cursor1[t] = sm[16 * t] - counts[16 * t];   // = boffs[16t]
}

// ===================== stage-1 partition: 62 super-buckets ===================
// Edge record (uu2): lo = col(0..17) | lr12(18..29); hi = q14.
// LDS-sorted tile + linear writeout: consecutive threads write consecutive
// global addresses within each of 62 runs -> full-line write combining.
__global__ __launch_bounds__(256) void part1(
        const int* __restrict__ rows, const int* __restrict__ cols,
        const float* __restrict__ vals, int* __restrict__ cursor1,
        uu2* __restrict__ ep1) {
    __shared__ uu2 dst[T1];              // 39.1 KB, LDS-sorted records
    __shared__ unsigned char sid[T1];    // 4.9 KB, super-bucket per slot
    __shared__ int cnt[NSUP], lbase[NSUP], gbase[NSUP], lcur[NSUP];
    int t = threadIdx.x;
    int tb = blockIdx.x * T1;
    int n = NNZ - tb; if (n <= 0) return; if (n > T1) n = T1;   // n % 4 == 0
    if (t < NSUP) cnt[t] = 0;
    __syncthreads();
    for (int i = t * 4; i < n; i += 1024) {          // pass A: count (int4)
        int4 r = *(const int4*)(rows + tb + i);
        atomicAdd(&cnt[r.x >> 12], 1);
        atomicAdd(&cnt[r.y >> 12], 1);
        atomicAdd(&cnt[r.z >> 12], 1);
        atomicAdd(&cnt[r.w >> 12], 1);
    }
    __syncthreads();
    if (t == 0) {                                    // local exclusive scan (62)
        int run = 0;
        for (int s = 0; s < NSUP; ++s) { lbase[s] = run; run += cnt[s]; }
    }
    __syncthreads();
    if (t < NSUP) {                                  // claim contiguous runs
        int c = cnt[t];
        gbase[t] = c ? atomicAdd(&cursor1[t], c) : 0;
        lcur[t] = 0;
    }
    __syncthreads();
    for (int i = t; i < n; i += 256) {               // pass B: rank into LDS
        int r = rows[tb + i];
        int s = r >> 12;
        int rank = atomicAdd(&lcur[s], 1);
        int p = lbase[s] + rank;
        uu2 e;
        e.x = (unsigned)cols[tb + i] | ((unsigned)(r & 4095) << 18);
        int q = (int)(vals[tb + i] * QSCALE + 0.5f);
        e.y = (unsigned)(q > 16383 ? 16383 : q);
        dst[p] = e;
        sid[p] = (unsigned char)s;
    }
    __syncthreads();
    for (int i = t; i < n; i += 256) {               // linear combined writeout
        int s = sid[i];
        int gpos = gbase[s] + (i - lbase[s]);
        __builtin_nontemporal_store(dst[i], ep1 + gpos);
    }
}

// ============== stage-2 partition: 16 sub-buckets per super-bucket ===========
// LDS-staged single read; 16 runs of ~320 edges fill lines fast in-block.
__global__ __launch_bounds__(256) void part2(
        const int* __restrict__ boffs, int* __restrict__ bcursor,
        const uu2* __restrict__ ep1, uu2* __restrict__ ep2) {
    __shared__ uu2 se[SCAP2];            // 44 KB
    __shared__ int cnt[16], base[16], cur[16];
    int b = blockIdx.x;
    int s = b >> 4, k = b & 15;
    int t = threadIdx.x;
    int sb0 = s * 16;
    int nsb = NCB - sb0; if (nsb > 16) nsb = 16;
    int beg = boffs[sb0];
    int end = boffs[sb0 + nsb];
    int n = end - beg;
    int chunk = (n + G2 - 1) / G2;
    int cb = beg + k * chunk;
    int ce = cb + chunk; if (ce > end) ce = end;
    if (cb >= ce) return;
    int m = ce - cb; if (m > SCAP2) m = SCAP2;       // +25 sigma, unreachable
    if (t < 16) cnt[t] = 0;
    __syncthreads();
    for (int i = t; i < m; i += 256) {               // stage + count
        uu2 e = ep1[cb + i];
        se[i] = e;
        atomicAdd(&cnt[(e.x >> 26) & 15], 1);
    }
    __syncthreads();
    if (t < 16) {
        int c = cnt[t];
        base[t] = c ? atomicAdd(&bcursor[sb0 + t], c) : 0;
        cur[t] = 0;
    }
    __syncthreads();
    for (int i = t; i < m; i += 256) {               // rank + write
        uu2 e = se[i];
        int j = (e.x >> 26) & 15;
        int rank = atomicAdd(&cur[j], 1);
        ep2[base[j] + rank] = e;
    }
}

// ============== per-sub-bucket in-LDS row sort -> final packed epk ===========
// epkF word: col (0..17) | q14 (18..31)
__global__ __launch_bounds__(256) void bucket_sort(const int* __restrict__ boffs,
                                                   const uu2* __restrict__ ep2,
                                                   unsigned* __restrict__ epkF,
                                                   int* __restrict__ offs) {
    __shared__ unsigned sx[SCAP];     // 24 KB (lo word)
    __shared__ ushort sv[SCAP];       // 12 KB (q14)
    __shared__ int cnt[256];
    __shared__ int base[256];
    __shared__ int cur[256];
    int b = blockIdx.x, t = threadIdx.x;
    int beg = boffs[b], end = boffs[b + 1];
    int n = end - beg; if (n > SCAP) n = SCAP;
    cnt[t] = 0;
    __syncthreads();
    for (int i = t; i < n; i += 256) {
        uu2 e = ep2[beg + i];
        sx[i] = e.x;
        sv[i] = (ushort)e.y;
        atomicAdd(&cnt[(e.x >> 18) & 0xFFu], 1);
    }
    __syncthreads();
    int c = cnt[t];
    base[t] = c; __syncthreads();
    for (int off = 1; off < 256; off <<= 1) {     // Hillis-Steele inclusive
        int v = (t >= off) ? base[t - off] : 0;
        __syncthreads();
        base[t] += v;
        __syncthreads();
    }
    int mybase = beg + base[t] - c;
    cur[t] = mybase;
    int r = b * 256 + t;
    if (r < NTOT) offs[r] = mybase;
    __syncthreads();
    for (int i = t; i < n; i += 256) {
        unsigned ex = sx[i];
        int lr = (int)((ex >> 18) & 0xFFu);
        int p = atomicAdd(&cur[lr], 1);
        epkF[p] = (ex & 0x3FFFFu) | ((unsigned)sv[i] << 18);
    }
}

// ======== convert: ego f32 -> fp8 xq (scaled), + f32 pass-throughs ==========
__global__ __launch_bounds__(256) void convert_kernel(
        const float* __restrict__ ue, const float* __restrict__ ie,
        const float* __restrict__ up, const float* __restrict__ ip,
        uu2* __restrict__ xq, float* __restrict__ out) {
    const int NG = NROW_ELEMS / 8;               // 2,000,000 8-elem groups
    int g = blockIdx.x * blockDim.x + threadIdx.x;
    if (g < NG) {
        int base = g * 8;
        const float* src = (base < USER_NUM * EMB) ? ue + base
                                                   : ie + (base - USER_NUM * EMB);
        ff4 a = __builtin_nontemporal_load((const ff4*)src);
        ff4 b = __builtin_nontemporal_load((const ff4*)src + 1);
        ff4* oc = (ff4*)(out + NROW_ELEMS + base);
        __builtin_nontemporal_store(a, oc);
        __builtin_nontemporal_store(b, oc + 1);
        float s[8] = {a.x * SCALE_F, a.y * SCALE_F, a.z * SCALE_F, a.w * SCALE_F,
                      b.x * SCALE_F, b.y * SCALE_F, b.z * SCALE_F, b.w * SCALE_F};
        uu2 w = enc8(s);
        __builtin_nontemporal_store(w, xq + g);
    } else {
        int pj = (g - NG) * 8;
        const float* src;
        float* dst;
        if (pj < PROTO_ELEMS) {
            src = up + pj; dst = out + 2 * NROW_ELEMS + pj;
        } else if (pj < 2 * PROTO_ELEMS) {
            src = ip + (pj - PROTO_ELEMS);
            dst = out + 2 * NROW_ELEMS + pj;
        } else return;
        ff4 a = __builtin_nontemporal_load((const ff4*)src);
        ff4 b = __builtin_nontemporal_load((const ff4*)src + 1);
        __builtin_nontemporal_store(a, (ff4*)dst);
        __builtin_nontemporal_store(b, (ff4*)dst + 1);
    }
}

// ===================== fp8-gather CSR SpMM (no atomics) ======================
// 8 lanes per row; lane l owns dims [8l, 8l+8): one uu2 (8 fp8) per edge.
// 8-deep software pipeline (at the measured ~50G lines/s gather ceiling).
template <int LAYER>
__global__ __launch_bounds__(256) void spmm_q(
        const uu2* __restrict__ src,         // fp8 gather source, 8 uu2/row
        const int* __restrict__ offs, const unsigned* __restrict__ epk,
        uu2* __restrict__ lq,                // layer output (L1/2)
        const float* __restrict__ ue, const float* __restrict__ ie,   // L3
        const uu2* __restrict__ l1q, const uu2* __restrict__ l2q,     // L3
        float* __restrict__ out) {           // L3
    int t = blockIdx.x * blockDim.x + threadIdx.x;
    int r = t >> 3, l = t & 7;
    if (r >= NTOT) return;
    int beg = offs[r], end = offs[r + 1];
    float acc[8] = {0.f, 0.f, 0.f, 0.f, 0.f, 0.f, 0.f, 0.f};
    int j = beg;
    for (; j + 7 < end; j += 8) {
        unsigned e[8];
#pragma unroll
        for (int k = 0; k < 8; ++k)
            e[k] = __builtin_nontemporal_load(epk + j + k);
        uu2 u[8];
#pragma unroll
        for (int k = 0; k < 8; ++k)
            u[k] = src[(e[k] & 0x3FFFFu) * 8 + l];
#pragma unroll
        for (int k = 0; k < 8; ++k)
            acc8q(acc, (float)(e[k] >> 18) * QSTEP, u[k]);
    }
    if (j + 3 < end) {
        unsigned e[4];
#pragma unroll
        for (int k = 0; k < 4; ++k)
            e[k] = __builtin_nontemporal_load(epk + j + k);
        uu2 u[4];
#pragma unroll
        for (int k = 0; k < 4; ++k)
            u[k] = src[(e[k] & 0x3FFFFu) * 8 + l];
#pragma unroll
        for (int k = 0; k < 4; ++k)
            acc8q(acc, (float)(e[k] >> 18) * QSTEP, u[k]);
        j += 4;
    }
    for (; j < end; ++j) {
        unsigned e0 = __builtin_nontemporal_load(epk + j);
        uu2 u0 = src[(e0 & 0x3FFFFu) * 8 + l];
        acc8q(acc, (float)(e0 >> 18) * QSTEP, u0);
    }
    int idx = r * 8 + l;
    if (LAYER == 1 || LAYER == 2) {
        uu2 w = enc8(acc);
        __builtin_nontemporal_store(w, lq + idx);
    } else {
        int base = r * EMB + l * 8;
        const float* ep = (r < USER_NUM) ? ue + base
                                         : ie + (base - USER_NUM * EMB);
        ff4 ea = __builtin_nontemporal_load((const ff4*)ep);
        ff4 eb = __builtin_nontemporal_load((const ff4*)ep + 1);
        uu2 u1 = __builtin_nontemporal_load(l1q + idx);
        uu2 u2 = __builtin_nontemporal_load(l2q + idx);
        float d1[8], d2[8];
        dec8(d1, u1);
        dec8(d2, u2);
        ff4 o0, o1;
        o0.x = ea.x * 0.25f + (d1[0] + d2[0] + acc[0]) * OUT_C;
        o0.y = ea.y * 0.25f + (d1[1] + d2[1] + acc[1]) * OUT_C;
        o0.z = ea.z * 0.25f + (d1[2] + d2[2] + acc[2]) * OUT_C;
        o0.w = ea.w * 0.25f + (d1[3] + d2[3] + acc[3]) * OUT_C;
        o1.x = eb.x * 0.25f + (d1[4] + d2[4] + acc[4]) * OUT_C;
        o1.y = eb.y * 0.25f + (d1[5] + d2[5] + acc[5]) * OUT_C;
        o1.z = eb.z * 0.25f + (d1[6] + d2[6] + acc[6]) * OUT_C;
        o1.w = eb.w * 0.25f + (d1[7] + d2[7] + acc[7]) * OUT_C;
        __builtin_nontemporal_store(o0, (ff4*)(out + base));
        __builtin_nontemporal_store(o1, (ff4*)(out + base) + 1);
    }
}

// =============================================================================
extern "C" void kernel_launch(void* const* d_in, const int* in_sizes, int n_in,
                              void* d_out, int out_size, void* d_ws, size_t ws_size,
                              hipStream_t stream) {
    const float* ue   = (const float*)d_in[0];
    const float* ie   = (const float*)d_in[1];
    const float* up   = (const float*)d_in[2];
    const float* ip   = (const float*)d_in[3];
    const float* vals = (const float*)d_in[4];
    const int*   rows = (const int*)d_in[5];
    const int*   cols = (const int*)d_in[6];
    float* out = (float*)d_out;

    // ws layout (4-byte units):
    //   [0, 10M)         ep1    : 5M uu2 stage-1 records (40 MB); epkF aliases
    //                             [0, 5M) after ep1 is dead
    //   [10M, 20M)       ep2    : 5M uu2 stage-2 records (40 MB)
    //   [20M, 24M)       xq     : fp8 ego (16 MB), ALIASED as l2q after spmm1
    //   [24M, 28M)       l1q    : fp8 layer-1 (16 MB)
    //   28,000,000       offs   : NTOT+1 row offsets
    //   28,250,112       boffs  : NCB+1
    //   28,252,000       bcursor: NCB
    //   28,253,000       bcounts: NCB
    //   28,254,000       cursor1: NSUP
    uu2*      ep1    = (uu2*)d_ws;
    uu2*      ep2    = (uu2*)((int*)d_ws + 10000000);
    unsigned* epkF   = (unsigned*)d_ws;              // aliases ep1 (dead)
    uu2*      xq     = (uu2*)((int*)d_ws + 20000000);
    uu2*      l1q    = (uu2*)((int*)d_ws + 24000000);
    int*      offs   = (int*)d_ws + 28000000;
    int*      boffs  = (int*)d_ws + 28250112;
    int*      bcursor= (int*)d_ws + 28252000;
    int*      bcounts= (int*)d_ws + 28253000;
    int*      cursor1= (int*)d_ws + 28254000;
    uu2*      l2q    = xq;                           // xq dead after spmm1

    const int sgrid = (NTOT * 8 + 255) / 256;        // 7813
    const int cgrid = (NROW_ELEMS / 8 + 2 * PROTO_ELEMS / 8 + 255) / 256;

    // ---- build row-sorted compressed CSR ----
    hipMemsetAsync(bcounts, 0, NCB * sizeof(int), stream);
    hist_kernel<<<256, 256, 0, stream>>>(rows, bcounts);
    scan_kernel<<<1, 1024, 0, stream>>>(bcounts, boffs, bcursor, cursor1, offs);
    part1      <<<NSB1, 256, 0, stream>>>(rows, cols, vals, cursor1, ep1);
    part2      <<<NSUP * G2, 256, 0, stream>>>(boffs, bcursor, ep1, ep2);
    bucket_sort<<<NCB, 256, 0, stream>>>(boffs, ep2, epkF, offs);

    // ---- convert ego to scaled fp8 + all f32 pass-through copies ----
    convert_kernel<<<cgrid, 256, 0, stream>>>(ue, ie, up, ip, xq, out);

    // ---- 3 fp8-gather SpMM layers; f32 assembly in layer 3 ----
    spmm_q<1><<<sgrid, 256, 0, stream>>>(xq,  offs, epkF, l1q,
                                         nullptr, nullptr, nullptr, nullptr, nullptr);
    spmm_q<2><<<sgrid, 256, 0, stream>>>(l1q, offs, epkF, l2q,
                                         nullptr, nullptr, nullptr, nullptr, nullptr);
    spmm_q<3><<<sgrid, 256, 0, stream>>>(l2q, offs, epkF, nullptr,
                                         ue, ie, l1q, l2q, out);
}